// Round 15
// baseline (196.637 us; speedup 1.0000x reference)
//
#include <hip/hip_runtime.h>

typedef __bf16 bf16x8 __attribute__((ext_vector_type(8)));
typedef float  f32x4  __attribute__((ext_vector_type(4)));
typedef float  f32x16 __attribute__((ext_vector_type(16)));
typedef unsigned u32x4 __attribute__((ext_vector_type(4)));

#define NB 4
#define SEQ 2048
#define EMB 1024
#define NH 16
#define HD 64
#define MTOT (NB * SEQ)   // 8192

__device__ __forceinline__ unsigned short f2bf(float f) {
    unsigned u = __float_as_uint(f);
    return (unsigned short)((u + 0x7fffu + ((u >> 16) & 1u)) >> 16);
}

__device__ __forceinline__ void gload16(const void* g, void* l) {
    __builtin_amdgcn_global_load_lds(
        (const __attribute__((address_space(1))) unsigned int*)g,
        (__attribute__((address_space(3))) unsigned int*)l,
        16, 0, 0);
}

// ------------------------------------------------------------- cast4 ----
// 4 weight matrices (1024x1024 each) in one launch. X is no longer cast:
// gemm_qkv reads f32 X directly and converts during staging.
__global__ __launch_bounds__(256) void cast4_f32_bf16(
    const float* __restrict__ a, const float* __restrict__ b,
    const float* __restrict__ c, const float* __restrict__ d,
    unsigned short* __restrict__ oa, unsigned short* __restrict__ ob,
    unsigned short* __restrict__ oc, unsigned short* __restrict__ od) {
    int which = blockIdx.x >> 10;
    int i = (blockIdx.x & 1023) * 256 + threadIdx.x;
    const float* src = which == 0 ? a : which == 1 ? b : which == 2 ? c : d;
    unsigned short* dst = which == 0 ? oa : which == 1 ? ob : which == 2 ? oc : od;
    float4 v = ((const float4*)src)[i];
    ushort4 r;
    r.x = f2bf(v.x); r.y = f2bf(v.y); r.z = f2bf(v.z); r.w = f2bf(v.w);
    ((ushort4*)dst)[i] = r;
}

// ---------------------------------------------------------- fused QKV ----
// X: [8192 x 1024] f32 (converted to bf16 in-staging, RNE via cvt_pk);
// W3: [3072 x 1024] bf16 (Wq|Wk|Wv stacked rows).
// proj0 -> Q bf16 [B,H,S,D] scaled by log2(e)/8; proj1 -> K; proj2 -> V^T.
// 1-D grid, XCD swizzle: w = (f&7)*(NWG/8) + (f>>3).
// A-side: reg-stage f32 -> cvt_pk bf16 -> swizzled ds_write_b128
//   (content(r,slot) = A[r][(slot^(r&7))*8..], same invariant as gload path).
// B-side: global_load_lds with pre-swizzled source.
__global__ __launch_bounds__(256) void gemm_qkv(
    const float* __restrict__ Xf, const unsigned short* __restrict__ W3,
    const float* __restrict__ bq, const float* __restrict__ bk,
    const float* __restrict__ bv, unsigned short* __restrict__ Qo,
    unsigned short* __restrict__ Ko, unsigned short* __restrict__ Vto) {
    constexpr int K = EMB;
    __shared__ __align__(16) unsigned short As[128 * 64];
    __shared__ __align__(16) unsigned short Bs[128 * 64];

    const int lane = threadIdx.x & 63;
    const int wv   = threadIdx.x >> 6;
    const int wr   = wv >> 1, wc = wv & 1;
    const int f    = blockIdx.x;                   // 0..1535
    const int w    = (f & 7) * 192 + (f >> 3);     // XCD-contiguous work id
    const int m0   = (w / 24) * 128, n0 = (w % 24) * 128;
    const int proj = n0 >> 10;
    const float* bp = proj == 0 ? bq : proj == 1 ? bk : bv;
    const float oscale = proj == 0 ? 0.18033688011112043f : 1.0f;

    f32x4 acc[4][4];
#pragma unroll
    for (int a = 0; a < 4; ++a)
#pragma unroll
        for (int b = 0; b < 4; ++b) acc[a][b] = (f32x4){0.f, 0.f, 0.f, 0.f};

    const int gsw = ((lane & 7) ^ (lane >> 3)) * 8;   // pre-swizzled src col (B)
    for (int kt = 0; kt < K / 64; ++kt) {
        if (kt) __syncthreads();
        // B tile via global_load_lds (unchanged)
#pragma unroll
        for (int j = 0; j < 4; ++j) {
            int rb = (wv * 4 + j) * 8;
            int r  = rb + (lane >> 3);
            gload16(W3 + (size_t)(n0 + r) * K + kt * 64 + gsw, &Bs[rb * 64]);
        }
        // A tile: f32 load -> bf16 cvt_pk -> swizzled ds_write
#pragma unroll
        for (int j = 0; j < 4; ++j) {
            int gi   = j * 256 + (int)threadIdx.x;
            int r    = gi >> 3, slot = gi & 7;
            const float* src = Xf + (size_t)(m0 + r) * K + kt * 64 + ((slot ^ (r & 7)) * 8);
            float4 v0 = *(const float4*)src;
            float4 v1 = *(const float4*)(src + 4);
            unsigned p0, p1, p2, p3;
            asm("v_cvt_pk_bf16_f32 %0, %1, %2" : "=v"(p0) : "v"(v0.x), "v"(v0.y));
            asm("v_cvt_pk_bf16_f32 %0, %1, %2" : "=v"(p1) : "v"(v0.z), "v"(v0.w));
            asm("v_cvt_pk_bf16_f32 %0, %1, %2" : "=v"(p2) : "v"(v1.x), "v"(v1.y));
            asm("v_cvt_pk_bf16_f32 %0, %1, %2" : "=v"(p3) : "v"(v1.z), "v"(v1.w));
            u32x4 pk = {p0, p1, p2, p3};
            *(u32x4*)&As[r * 64 + slot * 8] = pk;
        }
        __syncthreads();
#pragma unroll
        for (int ks = 0; ks < 2; ++ks) {
            const int slot = ((ks * 4 + (lane >> 4)) ^ (lane & 7)) * 8;
            bf16x8 af[4], bf_[4];
#pragma unroll
            for (int x = 0; x < 4; ++x) {
                af[x]  = *(const bf16x8*)&As[(wr * 64 + x * 16 + (lane & 15)) * 64 + slot];
                bf_[x] = *(const bf16x8*)&Bs[(wc * 64 + x * 16 + (lane & 15)) * 64 + slot];
            }
#pragma unroll
            for (int mi = 0; mi < 4; ++mi)
#pragma unroll
                for (int ni = 0; ni < 4; ++ni)
                    acc[mi][ni] = __builtin_amdgcn_mfma_f32_16x16x32_bf16(
                        af[mi], bf_[ni], acc[mi][ni], 0, 0, 0);
        }
    }

#pragma unroll
    for (int mi = 0; mi < 4; ++mi) {
#pragma unroll
        for (int ni = 0; ni < 4; ++ni) {
            int n    = n0 + wc * 64 + ni * 16 + (lane & 15);
            int nloc = n & 1023;
            float bvv = bp[nloc];
            int h = nloc >> 6, d = nloc & 63;
#pragma unroll
            for (int i = 0; i < 4; ++i) {
                int m = m0 + wr * 64 + mi * 16 + (lane >> 4) * 4 + i;
                float v = (acc[mi][ni][i] + bvv) * oscale;
                int b = m >> 11, s = m & (SEQ - 1);
                if (proj == 0)
                    Qo[(((size_t)(b * NH + h) * SEQ + s) << 6) + d] = f2bf(v);
                else if (proj == 1)
                    Ko[(((size_t)(b * NH + h) * SEQ + s) << 6) + d] = f2bf(v);
                else
                    Vto[((size_t)(b * NH + h) * 64 + d) * SEQ + s] = f2bf(v);
            }
        }
    }
}

// ------------------------------------------------------- final proj GEMM ----
__global__ __launch_bounds__(256) void gemm_out(
    const unsigned short* __restrict__ A, const unsigned short* __restrict__ W,
    const float* __restrict__ bias, float* __restrict__ out) {
    constexpr int K = EMB;
    __shared__ __align__(16) unsigned short As[128 * 64];
    __shared__ __align__(16) unsigned short Bs[128 * 64];

    const int lane = threadIdx.x & 63;
    const int wv   = threadIdx.x >> 6;
    const int wr   = wv >> 1, wc = wv & 1;
    const int f    = blockIdx.x;                 // 0..511
    const int w    = (f & 7) * 64 + (f >> 3);    // XCD-contiguous work id
    const int m0   = (w / 8) * 128, n0 = (w % 8) * 128;

    f32x4 acc[4][4];
#pragma unroll
    for (int a = 0; a < 4; ++a)
#pragma unroll
        for (int b = 0; b < 4; ++b) acc[a][b] = (f32x4){0.f, 0.f, 0.f, 0.f};

    const int gsw = ((lane & 7) ^ (lane >> 3)) * 8;
    for (int kt = 0; kt < K / 64; ++kt) {
        if (kt) __syncthreads();
#pragma unroll
        for (int j = 0; j < 4; ++j) {
            int rb = (wv * 4 + j) * 8;
            int r  = rb + (lane >> 3);
            gload16(A + (size_t)(m0 + r) * K + kt * 64 + gsw, &As[rb * 64]);
            gload16(W + (size_t)(n0 + r) * K + kt * 64 + gsw, &Bs[rb * 64]);
        }
        __syncthreads();
#pragma unroll
        for (int ks = 0; ks < 2; ++ks) {
            const int slot = ((ks * 4 + (lane >> 4)) ^ (lane & 7)) * 8;
            bf16x8 af[4], bf_[4];
#pragma unroll
            for (int x = 0; x < 4; ++x) {
                af[x]  = *(const bf16x8*)&As[(wr * 64 + x * 16 + (lane & 15)) * 64 + slot];
                bf_[x] = *(const bf16x8*)&Bs[(wc * 64 + x * 16 + (lane & 15)) * 64 + slot];
            }
#pragma unroll
            for (int mi = 0; mi < 4; ++mi)
#pragma unroll
                for (int ni = 0; ni < 4; ++ni)
                    acc[mi][ni] = __builtin_amdgcn_mfma_f32_16x16x32_bf16(
                        af[mi], bf_[ni], acc[mi][ni], 0, 0, 0);
        }
    }

#pragma unroll
    for (int mi = 0; mi < 4; ++mi) {
#pragma unroll
        for (int ni = 0; ni < 4; ++ni) {
            int n = n0 + wc * 64 + ni * 16 + (lane & 15);
            float bv = bias[n];
#pragma unroll
            for (int i = 0; i < 4; ++i) {
                int m = m0 + wr * 64 + mi * 16 + (lane >> 4) * 4 + i;
                out[(size_t)m * EMB + n] = acc[mi][ni][i] + bv;
            }
        }
    }
}

// ----------------------------------------------------------- attention ----
// VERIFIED R14 version (83us, absmax 4.88e-4, 0 bank conflicts).
// R9 structure + l-via-MFMA: lT = mfma(ones, pf) accumulates P column-sums
// on the matrix pipe. 512 threads, 8 waves, 32 q per wave. 1-D grid, bh in
// LOW 6 bits (XCD). Granule-major LDS. Fixed-max softmax p = exp2(s).
// Q: [B,H,S,D] bf16 PRE-SCALED by log2(e)/8; K: [B,H,S,D]; Vt: [B,H,D,S];
// AO: [B,S,H,D] bf16.
__global__ __launch_bounds__(512, 4) void attn_fwd(
    const unsigned short* __restrict__ Q, const unsigned short* __restrict__ K,
    const unsigned short* __restrict__ Vt, unsigned short* __restrict__ AO) {
    const int qt = blockIdx.x >> 6;   // 0..7 (q tile of 256)
    const int bh = blockIdx.x & 63;   // low bits -> XCD locality
    const int lane = threadIdx.x & 63;
    const int wv   = threadIdx.x >> 6;   // 0..7
    const int l31  = lane & 31;
    const int lh   = lane >> 5;

    __shared__ __align__(16) unsigned short Ks[2][8 * 64 * 8];  // [g][kv][8]
    __shared__ __align__(16) unsigned short Vs[2][8 * 64 * 8];  // [g][d][8]

    const unsigned short* Kb = K + (size_t)bh * SEQ * HD;
    const unsigned short* Vb = Vt + (size_t)bh * HD * SEQ;

    // Q B-fragments (col=q=l31, k=d): lane's q-row, half-k slice per lh
    const unsigned short* Qp = Q + ((size_t)bh * SEQ + qt * 256 + wv * 32 + l31) * HD + lh * 8;
    bf16x8 qfr[4];
#pragma unroll
    for (int kc = 0; kc < 4; ++kc) qfr[kc] = *(const bf16x8*)(Qp + kc * 16);

    // ones A-fragment (bf16 1.0 = 0x3F80)
    const u32x4 onesu = {0x3F803F80u, 0x3F803F80u, 0x3F803F80u, 0x3F803F80u};
    const bf16x8 ones = __builtin_bit_cast(bf16x8, onesu);

    f32x16 oT[2], lT;
#pragma unroll
    for (int r = 0; r < 16; ++r) { oT[0][r] = 0.f; oT[1][r] = 0.f; lT[r] = 0.f; }

    // wave w stages K-granule w (d cols w*8..w*8+7 for all 64 kv) and
    // V-granule w (kv cols t*64+w*8.. for all 64 d); linear LDS dest.
    auto stageKV = [&](int buf, int t) {
        gload16(Kb + (size_t)(t * 64 + lane) * HD + wv * 8, &Ks[buf][wv * 512]);
        gload16(Vb + (size_t)lane * SEQ + t * 64 + wv * 8, &Vs[buf][wv * 512]);
    };

    stageKV(0, 0);

    for (int t = 0; t < SEQ / 64; ++t) {
        const int cur = t & 1;
        __syncthreads();
        if (t + 1 < SEQ / 64) stageKV(cur ^ 1, t + 1);

#pragma unroll
        for (int sub = 0; sub < 2; ++sub) {
            // S^T(32kv x 32q) = K_sub · Q^T ; kf granule g = kc*2+lh, row = krow
            f32x16 st;
#pragma unroll
            for (int r = 0; r < 16; ++r) st[r] = 0.f;
            const int krow = sub * 32 + l31;
            __builtin_amdgcn_s_setprio(1);
#pragma unroll
            for (int kc = 0; kc < 4; ++kc) {
                bf16x8 kf = *(const bf16x8*)&Ks[cur][(kc * 2 + lh) * 512 + krow * 8];
                st = __builtin_amdgcn_mfma_f32_32x32x16_bf16(kf, qfr[kc], st, 0, 0, 0);
            }
            __builtin_amdgcn_s_setprio(0);

            // p = exp2(st); pack pairs to bf16 (q lane-local)
            unsigned w0, w1, w2, w3, w4, w5, w6, w7;
#define EXPPK(WI, RA, RB)                                                     \
            {                                                                 \
                float pa = __builtin_amdgcn_exp2f(st[RA]);                    \
                float pb = __builtin_amdgcn_exp2f(st[RB]);                    \
                asm("v_cvt_pk_bf16_f32 %0, %1, %2" : "=v"(WI) : "v"(pa), "v"(pb)); \
            }
            EXPPK(w0, 0, 1)  EXPPK(w1, 2, 3)  EXPPK(w2, 4, 5)  EXPPK(w3, 6, 7)
            EXPPK(w4, 8, 9)  EXPPK(w5, 10, 11) EXPPK(w6, 12, 13) EXPPK(w7, 14, 15)
#undef EXPPK
            asm volatile("v_permlane32_swap_b32 %0, %1" : "+v"(w0), "+v"(w2));
            asm volatile("v_permlane32_swap_b32 %0, %1" : "+v"(w1), "+v"(w3));
            asm volatile("v_permlane32_swap_b32 %0, %1" : "+v"(w4), "+v"(w6));
            asm volatile("v_permlane32_swap_b32 %0, %1" : "+v"(w5), "+v"(w7));
            u32x4 a0 = {w0, w1, w2, w3};
            u32x4 a1 = {w4, w5, w6, w7};
            bf16x8 pf0 = __builtin_bit_cast(bf16x8, a0);
            bf16x8 pf1 = __builtin_bit_cast(bf16x8, a1);

            // O^T += V^T_sub · P^T ; l += 1^T · P^T  (all on the MFMA pipe)
            __builtin_amdgcn_s_setprio(1);
            lT = __builtin_amdgcn_mfma_f32_32x32x16_bf16(ones, pf0, lT, 0, 0, 0);
            lT = __builtin_amdgcn_mfma_f32_32x32x16_bf16(ones, pf1, lT, 0, 0, 0);
#pragma unroll
            for (int dt = 0; dt < 2; ++dt) {
                int d = dt * 32 + l31;
#pragma unroll
                for (int ks = 0; ks < 2; ++ks) {
                    bf16x8 vf = *(const bf16x8*)&Vs[cur][(sub * 4 + ks * 2 + lh) * 512 + d * 8];
                    oT[dt] = __builtin_amdgcn_mfma_f32_32x32x16_bf16(
                        vf, ks ? pf1 : pf0, oT[dt], 0, 0, 0);
                }
            }
            __builtin_amdgcn_s_setprio(0);
        }
    }

    // l = lT[0] (every C row is the full colsum); divide and store O^T
    float inv = 1.0f / lT[0];
    const int b = bh >> 4, h = bh & 15;
    const int q = qt * 256 + wv * 32 + l31;
    unsigned short* aor = AO + (((size_t)b * SEQ + q) * NH + h) * HD;
#pragma unroll
    for (int dt = 0; dt < 2; ++dt) {
#pragma unroll
        for (int g = 0; g < 4; ++g) {
            ushort4 o;
            o.x = f2bf(oT[dt][g * 4 + 0] * inv);
            o.y = f2bf(oT[dt][g * 4 + 1] * inv);
            o.z = f2bf(oT[dt][g * 4 + 2] * inv);
            o.w = f2bf(oT[dt][g * 4 + 3] * inv);
            *(ushort4*)(aor + dt * 32 + g * 8 + lh * 4) = o;
        }
    }
}

// -------------------------------------------------------------- launch ----
extern "C" void kernel_launch(void* const* d_in, const int* in_sizes, int n_in,
                              void* d_out, int out_size, void* d_ws, size_t ws_size,
                              hipStream_t stream) {
    const float* X  = (const float*)d_in[0];
    const float* wq = (const float*)d_in[1];
    const float* bq = (const float*)d_in[2];
    const float* wk = (const float*)d_in[3];
    const float* bk = (const float*)d_in[4];
    const float* wv = (const float*)d_in[5];
    const float* bv = (const float*)d_in[6];
    const float* wo = (const float*)d_in[7];
    const float* bo = (const float*)d_in[8];
    float* out = (float*)d_out;

    unsigned short* ws = (unsigned short*)d_ws;
    const size_t XE = (size_t)MTOT * EMB;      // 8388608
    const size_t WE = (size_t)EMB * EMB;       // 1048576
    unsigned short* AOb = ws;                  // attn output (Xb slot, no X cast)
    unsigned short* Wqb = ws + XE;             // Wq|Wk|Wv contiguous = W3
    unsigned short* Wkb = Wqb + WE;
    unsigned short* Wvb = Wkb + WE;
    unsigned short* Wob = Wvb + WE;
    unsigned short* Qb  = Wob + WE;
    unsigned short* Kb  = Qb + XE;
    unsigned short* Vtb = Kb + XE;

    cast4_f32_bf16<<<4096, 256, 0, stream>>>(wq, wk, wv, wo, Wqb, Wkb, Wvb, Wob);

    gemm_qkv<<<1536, 256, 0, stream>>>(X, Wqb, bq, bk, bv, Qb, Kb, Vtb);

    attn_fwd<<<512, 512, 0, stream>>>(Qb, Kb, Vtb, AOb);

    gemm_out<<<512, 256, 0, stream>>>(AOb, Wob, bo, out);
}

// Round 16
// 183.930 us; speedup vs baseline: 1.0691x; 1.0691x over previous
//
#include <hip/hip_runtime.h>

typedef __bf16 bf16x8 __attribute__((ext_vector_type(8)));
typedef float  f32x4  __attribute__((ext_vector_type(4)));
typedef float  f32x16 __attribute__((ext_vector_type(16)));
typedef unsigned u32x4 __attribute__((ext_vector_type(4)));

#define NB 4
#define SEQ 2048
#define EMB 1024
#define NH 16
#define HD 64
#define MTOT (NB * SEQ)   // 8192

__device__ __forceinline__ unsigned short f2bf(float f) {
    unsigned u = __float_as_uint(f);
    return (unsigned short)((u + 0x7fffu + ((u >> 16) & 1u)) >> 16);
}

__device__ __forceinline__ void gload16(const void* g, void* l) {
    __builtin_amdgcn_global_load_lds(
        (const __attribute__((address_space(1))) unsigned int*)g,
        (__attribute__((address_space(3))) unsigned int*)l,
        16, 0, 0);
}

// ------------------------------------------------------------- cast all ----
// One launch: X (8192 blocks) + 4 weight matrices (1024 blocks each).
__global__ __launch_bounds__(256) void cast_all(
    const float* __restrict__ X, const float* __restrict__ a,
    const float* __restrict__ b, const float* __restrict__ c,
    const float* __restrict__ d, unsigned short* __restrict__ oX,
    unsigned short* __restrict__ oa, unsigned short* __restrict__ ob,
    unsigned short* __restrict__ oc, unsigned short* __restrict__ od) {
    int blk = blockIdx.x;
    const float* src;
    unsigned short* dst;
    int i;
    if (blk < 8192) {
        src = X; dst = oX; i = blk * 256 + threadIdx.x;
    } else {
        int wblk = blk - 8192;
        int which = wblk >> 10;
        src = which == 0 ? a : which == 1 ? b : which == 2 ? c : d;
        dst = which == 0 ? oa : which == 1 ? ob : which == 2 ? oc : od;
        i = (wblk & 1023) * 256 + threadIdx.x;
    }
    float4 v = ((const float4*)src)[i];
    ushort4 r;
    r.x = f2bf(v.x); r.y = f2bf(v.y); r.z = f2bf(v.z); r.w = f2bf(v.w);
    ((ushort4*)dst)[i] = r;
}

// ---------------------------------------------------------- fused QKV ----
// A: [8192 x 1024] bf16; W3: [3072 x 1024] bf16 (Wq|Wk|Wv stacked rows).
// proj0 -> Q bf16 [B,H,S,D] scaled by log2(e)/8; proj1 -> K; proj2 -> V^T.
// 1-D grid, XCD swizzle: w = (f&7)*(NWG/8) + (f>>3).
__global__ __launch_bounds__(256) void gemm_qkv(
    const unsigned short* __restrict__ A, const unsigned short* __restrict__ W3,
    const float* __restrict__ bq, const float* __restrict__ bk,
    const float* __restrict__ bv, unsigned short* __restrict__ Qo,
    unsigned short* __restrict__ Ko, unsigned short* __restrict__ Vto) {
    constexpr int K = EMB;
    __shared__ __align__(16) unsigned short As[128 * 64];
    __shared__ __align__(16) unsigned short Bs[128 * 64];

    const int lane = threadIdx.x & 63;
    const int wv   = threadIdx.x >> 6;
    const int wr   = wv >> 1, wc = wv & 1;
    const int f    = blockIdx.x;                   // 0..1535
    const int w    = (f & 7) * 192 + (f >> 3);     // XCD-contiguous work id
    const int m0   = (w / 24) * 128, n0 = (w % 24) * 128;
    const int proj = n0 >> 10;
    const float* bp = proj == 0 ? bq : proj == 1 ? bk : bv;
    const float oscale = proj == 0 ? 0.18033688011112043f : 1.0f;

    f32x4 acc[4][4];
#pragma unroll
    for (int a = 0; a < 4; ++a)
#pragma unroll
        for (int b = 0; b < 4; ++b) acc[a][b] = (f32x4){0.f, 0.f, 0.f, 0.f};

    const int gsw = ((lane & 7) ^ (lane >> 3)) * 8;   // pre-swizzled src col
    for (int kt = 0; kt < K / 64; ++kt) {
        if (kt) __syncthreads();
#pragma unroll
        for (int j = 0; j < 4; ++j) {
            int rb = (wv * 4 + j) * 8;
            int r  = rb + (lane >> 3);
            gload16(A + (size_t)(m0 + r) * K + kt * 64 + gsw, &As[rb * 64]);
            gload16(W3 + (size_t)(n0 + r) * K + kt * 64 + gsw, &Bs[rb * 64]);
        }
        __syncthreads();
#pragma unroll
        for (int ks = 0; ks < 2; ++ks) {
            const int slot = ((ks * 4 + (lane >> 4)) ^ (lane & 7)) * 8;
            bf16x8 af[4], bf_[4];
#pragma unroll
            for (int x = 0; x < 4; ++x) {
                af[x]  = *(const bf16x8*)&As[(wr * 64 + x * 16 + (lane & 15)) * 64 + slot];
                bf_[x] = *(const bf16x8*)&Bs[(wc * 64 + x * 16 + (lane & 15)) * 64 + slot];
            }
#pragma unroll
            for (int mi = 0; mi < 4; ++mi)
#pragma unroll
                for (int ni = 0; ni < 4; ++ni)
                    acc[mi][ni] = __builtin_amdgcn_mfma_f32_16x16x32_bf16(
                        af[mi], bf_[ni], acc[mi][ni], 0, 0, 0);
        }
    }

#pragma unroll
    for (int mi = 0; mi < 4; ++mi) {
#pragma unroll
        for (int ni = 0; ni < 4; ++ni) {
            int n    = n0 + wc * 64 + ni * 16 + (lane & 15);
            int nloc = n & 1023;
            float bvv = bp[nloc];
            int h = nloc >> 6, d = nloc & 63;
#pragma unroll
            for (int i = 0; i < 4; ++i) {
                int m = m0 + wr * 64 + mi * 16 + (lane >> 4) * 4 + i;
                float v = (acc[mi][ni][i] + bvv) * oscale;
                int b = m >> 11, s = m & (SEQ - 1);
                if (proj == 0)
                    Qo[(((size_t)(b * NH + h) * SEQ + s) << 6) + d] = f2bf(v);
                else if (proj == 1)
                    Ko[(((size_t)(b * NH + h) * SEQ + s) << 6) + d] = f2bf(v);
                else
                    Vto[((size_t)(b * NH + h) * 64 + d) * SEQ + s] = f2bf(v);
            }
        }
    }
}

// ------------------------------------------------------- final proj GEMM ----
__global__ __launch_bounds__(256) void gemm_out(
    const unsigned short* __restrict__ A, const unsigned short* __restrict__ W,
    const float* __restrict__ bias, float* __restrict__ out) {
    constexpr int K = EMB;
    __shared__ __align__(16) unsigned short As[128 * 64];
    __shared__ __align__(16) unsigned short Bs[128 * 64];

    const int lane = threadIdx.x & 63;
    const int wv   = threadIdx.x >> 6;
    const int wr   = wv >> 1, wc = wv & 1;
    const int f    = blockIdx.x;                 // 0..511
    const int w    = (f & 7) * 64 + (f >> 3);    // XCD-contiguous work id
    const int m0   = (w / 8) * 128, n0 = (w % 8) * 128;

    f32x4 acc[4][4];
#pragma unroll
    for (int a = 0; a < 4; ++a)
#pragma unroll
        for (int b = 0; b < 4; ++b) acc[a][b] = (f32x4){0.f, 0.f, 0.f, 0.f};

    const int gsw = ((lane & 7) ^ (lane >> 3)) * 8;
    for (int kt = 0; kt < K / 64; ++kt) {
        if (kt) __syncthreads();
#pragma unroll
        for (int j = 0; j < 4; ++j) {
            int rb = (wv * 4 + j) * 8;
            int r  = rb + (lane >> 3);
            gload16(A + (size_t)(m0 + r) * K + kt * 64 + gsw, &As[rb * 64]);
            gload16(W + (size_t)(n0 + r) * K + kt * 64 + gsw, &Bs[rb * 64]);
        }
        __syncthreads();
#pragma unroll
        for (int ks = 0; ks < 2; ++ks) {
            const int slot = ((ks * 4 + (lane >> 4)) ^ (lane & 7)) * 8;
            bf16x8 af[4], bf_[4];
#pragma unroll
            for (int x = 0; x < 4; ++x) {
                af[x]  = *(const bf16x8*)&As[(wr * 64 + x * 16 + (lane & 15)) * 64 + slot];
                bf_[x] = *(const bf16x8*)&Bs[(wc * 64 + x * 16 + (lane & 15)) * 64 + slot];
            }
#pragma unroll
            for (int mi = 0; mi < 4; ++mi)
#pragma unroll
                for (int ni = 0; ni < 4; ++ni)
                    acc[mi][ni] = __builtin_amdgcn_mfma_f32_16x16x32_bf16(
                        af[mi], bf_[ni], acc[mi][ni], 0, 0, 0);
        }
    }

#pragma unroll
    for (int mi = 0; mi < 4; ++mi) {
#pragma unroll
        for (int ni = 0; ni < 4; ++ni) {
            int n = n0 + wc * 64 + ni * 16 + (lane & 15);
            float bv = bias[n];
#pragma unroll
            for (int i = 0; i < 4; ++i) {
                int m = m0 + wr * 64 + mi * 16 + (lane >> 4) * 4 + i;
                out[(size_t)m * EMB + n] = acc[mi][ni][i] + bv;
            }
        }
    }
}

// ----------------------------------------------------------- attention ----
// R14 structure (verified) with KVB 64 -> 128: pure parameter change of the
// same double-buffered template -> halves the __syncthreads count (32->16
// full vmcnt/lgkm drains). LDS 64KB; grid is 2 blocks/CU and 160/64=2, so
// residency unchanged.
//   Ks[buf][g][kv][8]: g = d-granule (8), kv = 0..127.  wave w stages
//     granule w in two 64-row halves (2 gloads).
//   Vs[buf][g][d][8]:  g = kv-granule (16), d = 0..63.  wave w stages
//     granules 2w, 2w+1 (2 gloads).
// l-via-MFMA: lT = mfma(ones, pf) on the matrix pipe. 512 threads, 8 waves,
// 32 q per wave. 1-D grid, bh in LOW 6 bits (XCD). Fixed-max softmax.
// Q: [B,H,S,D] bf16 PRE-SCALED by log2(e)/8; K: [B,H,S,D]; Vt: [B,H,D,S];
// AO: [B,S,H,D] bf16.
__global__ __launch_bounds__(512, 2) void attn_fwd(
    const unsigned short* __restrict__ Q, const unsigned short* __restrict__ K,
    const unsigned short* __restrict__ Vt, unsigned short* __restrict__ AO) {
    const int qt = blockIdx.x >> 6;   // 0..7 (q tile of 256)
    const int bh = blockIdx.x & 63;   // low bits -> XCD locality
    const int lane = threadIdx.x & 63;
    const int wv   = threadIdx.x >> 6;   // 0..7
    const int l31  = lane & 31;
    const int lh   = lane >> 5;
    constexpr int NT = SEQ / 128;     // 16 kv tiles of 128

    __shared__ __align__(16) unsigned short Ks[2][8 * 128 * 8];   // [g][kv][8]
    __shared__ __align__(16) unsigned short Vs[2][16 * 64 * 8];   // [g][d][8]

    const unsigned short* Kb = K + (size_t)bh * SEQ * HD;
    const unsigned short* Vb = Vt + (size_t)bh * HD * SEQ;

    // Q B-fragments (col=q=l31, k=d): lane's q-row, half-k slice per lh
    const unsigned short* Qp = Q + ((size_t)bh * SEQ + qt * 256 + wv * 32 + l31) * HD + lh * 8;
    bf16x8 qfr[4];
#pragma unroll
    for (int kc = 0; kc < 4; ++kc) qfr[kc] = *(const bf16x8*)(Qp + kc * 16);

    // ones A-fragment (bf16 1.0 = 0x3F80)
    const u32x4 onesu = {0x3F803F80u, 0x3F803F80u, 0x3F803F80u, 0x3F803F80u};
    const bf16x8 ones = __builtin_bit_cast(bf16x8, onesu);

    f32x16 oT[2], lT;
#pragma unroll
    for (int r = 0; r < 16; ++r) { oT[0][r] = 0.f; oT[1][r] = 0.f; lT[r] = 0.f; }

    // K granule w: rows t*128+half*64+lane, cols w*8..w*8+7 (2 gloads).
    // V granules 2w,2w+1: kv = t*128+g*8..+7 for all 64 d (2 gloads).
    auto stageKV = [&](int buf, int t) {
#pragma unroll
        for (int half = 0; half < 2; ++half)
            gload16(Kb + (size_t)(t * 128 + half * 64 + lane) * HD + wv * 8,
                    &Ks[buf][wv * 1024 + half * 512]);
#pragma unroll
        for (int j = 0; j < 2; ++j) {
            int g = wv * 2 + j;
            gload16(Vb + (size_t)lane * SEQ + t * 128 + g * 8, &Vs[buf][g * 512]);
        }
    };

    stageKV(0, 0);

    for (int t = 0; t < NT; ++t) {
        const int cur = t & 1;
        __syncthreads();
        if (t + 1 < NT) stageKV(cur ^ 1, t + 1);

#pragma unroll
        for (int sub = 0; sub < 4; ++sub) {
            // S^T(32kv x 32q) = K_sub · Q^T ; kf granule g = kc*2+lh, row = krow
            f32x16 st;
#pragma unroll
            for (int r = 0; r < 16; ++r) st[r] = 0.f;
            const int krow = sub * 32 + l31;
            __builtin_amdgcn_s_setprio(1);
#pragma unroll
            for (int kc = 0; kc < 4; ++kc) {
                bf16x8 kf = *(const bf16x8*)&Ks[cur][(kc * 2 + lh) * 1024 + krow * 8];
                st = __builtin_amdgcn_mfma_f32_32x32x16_bf16(kf, qfr[kc], st, 0, 0, 0);
            }
            __builtin_amdgcn_s_setprio(0);

            // p = exp2(st); pack pairs to bf16 (q lane-local)
            unsigned w0, w1, w2, w3, w4, w5, w6, w7;
#define EXPPK(WI, RA, RB)                                                     \
            {                                                                 \
                float pa = __builtin_amdgcn_exp2f(st[RA]);                    \
                float pb = __builtin_amdgcn_exp2f(st[RB]);                    \
                asm("v_cvt_pk_bf16_f32 %0, %1, %2" : "=v"(WI) : "v"(pa), "v"(pb)); \
            }
            EXPPK(w0, 0, 1)  EXPPK(w1, 2, 3)  EXPPK(w2, 4, 5)  EXPPK(w3, 6, 7)
            EXPPK(w4, 8, 9)  EXPPK(w5, 10, 11) EXPPK(w6, 12, 13) EXPPK(w7, 14, 15)
#undef EXPPK
            asm volatile("v_permlane32_swap_b32 %0, %1" : "+v"(w0), "+v"(w2));
            asm volatile("v_permlane32_swap_b32 %0, %1" : "+v"(w1), "+v"(w3));
            asm volatile("v_permlane32_swap_b32 %0, %1" : "+v"(w4), "+v"(w6));
            asm volatile("v_permlane32_swap_b32 %0, %1" : "+v"(w5), "+v"(w7));
            u32x4 a0 = {w0, w1, w2, w3};
            u32x4 a1 = {w4, w5, w6, w7};
            bf16x8 pf0 = __builtin_bit_cast(bf16x8, a0);
            bf16x8 pf1 = __builtin_bit_cast(bf16x8, a1);

            // O^T += V^T_sub · P^T ; l += 1^T · P^T  (all on the MFMA pipe)
            __builtin_amdgcn_s_setprio(1);
            lT = __builtin_amdgcn_mfma_f32_32x32x16_bf16(ones, pf0, lT, 0, 0, 0);
            lT = __builtin_amdgcn_mfma_f32_32x32x16_bf16(ones, pf1, lT, 0, 0, 0);
#pragma unroll
            for (int dt = 0; dt < 2; ++dt) {
                int d = dt * 32 + l31;
#pragma unroll
                for (int ks = 0; ks < 2; ++ks) {
                    bf16x8 vf = *(const bf16x8*)&Vs[cur][(sub * 4 + ks * 2 + lh) * 512 + d * 8];
                    oT[dt] = __builtin_amdgcn_mfma_f32_32x32x16_bf16(
                        vf, ks ? pf1 : pf0, oT[dt], 0, 0, 0);
                }
            }
            __builtin_amdgcn_s_setprio(0);
        }
    }

    // l = lT[0] (every C row is the full colsum); divide and store O^T
    float inv = 1.0f / lT[0];
    const int b = bh >> 4, h = bh & 15;
    const int q = qt * 256 + wv * 32 + l31;
    unsigned short* aor = AO + (((size_t)b * SEQ + q) * NH + h) * HD;
#pragma unroll
    for (int dt = 0; dt < 2; ++dt) {
#pragma unroll
        for (int g = 0; g < 4; ++g) {
            ushort4 o;
            o.x = f2bf(oT[dt][g * 4 + 0] * inv);
            o.y = f2bf(oT[dt][g * 4 + 1] * inv);
            o.z = f2bf(oT[dt][g * 4 + 2] * inv);
            o.w = f2bf(oT[dt][g * 4 + 3] * inv);
            *(ushort4*)(aor + dt * 32 + g * 8 + lh * 4) = o;
        }
    }
}

// -------------------------------------------------------------- launch ----
extern "C" void kernel_launch(void* const* d_in, const int* in_sizes, int n_in,
                              void* d_out, int out_size, void* d_ws, size_t ws_size,
                              hipStream_t stream) {
    const float* X  = (const float*)d_in[0];
    const float* wq = (const float*)d_in[1];
    const float* bq = (const float*)d_in[2];
    const float* wk = (const float*)d_in[3];
    const float* bk = (const float*)d_in[4];
    const float* wv = (const float*)d_in[5];
    const float* bv = (const float*)d_in[6];
    const float* wo = (const float*)d_in[7];
    const float* bo = (const float*)d_in[8];
    float* out = (float*)d_out;

    unsigned short* ws = (unsigned short*)d_ws;
    const size_t XE = (size_t)MTOT * EMB;      // 8388608
    const size_t WE = (size_t)EMB * EMB;       // 1048576
    unsigned short* Xb  = ws;
    unsigned short* Wqb = ws + XE;             // Wq|Wk|Wv contiguous = W3
    unsigned short* Wkb = Wqb + WE;
    unsigned short* Wvb = Wkb + WE;
    unsigned short* Wob = Wvb + WE;
    unsigned short* Qb  = Wob + WE;
    unsigned short* Kb  = Qb + XE;
    unsigned short* Vtb = Kb + XE;
    unsigned short* AOb = Xb;                  // alias: Xb dead after QKV proj

    cast_all<<<12288, 256, 0, stream>>>(X, wq, wk, wv, wo, Xb, Wqb, Wkb, Wvb, Wob);

    gemm_qkv<<<1536, 256, 0, stream>>>(Xb, Wqb, bq, bk, bv, Qb, Kb, Vtb);

    attn_fwd<<<512, 512, 0, stream>>>(Qb, Kb, Vtb, AOb);

    gemm_out<<<512, 256, 0, stream>>>(AOb, Wob, bo, out);
}

// Round 17
// 182.048 us; speedup vs baseline: 1.0801x; 1.0103x over previous
//
#include <hip/hip_runtime.h>

typedef __bf16 bf16x8 __attribute__((ext_vector_type(8)));
typedef float  f32x4  __attribute__((ext_vector_type(4)));
typedef float  f32x16 __attribute__((ext_vector_type(16)));
typedef unsigned u32x4 __attribute__((ext_vector_type(4)));

#define NB 4
#define SEQ 2048
#define EMB 1024
#define NH 16
#define HD 64
#define MTOT (NB * SEQ)   // 8192

__device__ __forceinline__ unsigned short f2bf(float f) {
    unsigned u = __float_as_uint(f);
    return (unsigned short)((u + 0x7fffu + ((u >> 16) & 1u)) >> 16);
}

__device__ __forceinline__ void gload16(const void* g, void* l) {
    __builtin_amdgcn_global_load_lds(
        (const __attribute__((address_space(1))) unsigned int*)g,
        (__attribute__((address_space(3))) unsigned int*)l,
        16, 0, 0);
}

// ------------------------------------------------------------- cast all ----
// One launch: X (8192 blocks) + 4 weight matrices (1024 blocks each).
__global__ __launch_bounds__(256) void cast_all(
    const float* __restrict__ X, const float* __restrict__ a,
    const float* __restrict__ b, const float* __restrict__ c,
    const float* __restrict__ d, unsigned short* __restrict__ oX,
    unsigned short* __restrict__ oa, unsigned short* __restrict__ ob,
    unsigned short* __restrict__ oc, unsigned short* __restrict__ od) {
    int blk = blockIdx.x;
    const float* src;
    unsigned short* dst;
    int i;
    if (blk < 8192) {
        src = X; dst = oX; i = blk * 256 + threadIdx.x;
    } else {
        int wblk = blk - 8192;
        int which = wblk >> 10;
        src = which == 0 ? a : which == 1 ? b : which == 2 ? c : d;
        dst = which == 0 ? oa : which == 1 ? ob : which == 2 ? oc : od;
        i = (wblk & 1023) * 256 + threadIdx.x;
    }
    float4 v = ((const float4*)src)[i];
    ushort4 r;
    r.x = f2bf(v.x); r.y = f2bf(v.y); r.z = f2bf(v.z); r.w = f2bf(v.w);
    ((ushort4*)dst)[i] = r;
}

// ---------------------------------------------------------- fused QKV ----
// A: [8192 x 1024] bf16; W3: [3072 x 1024] bf16 (Wq|Wk|Wv stacked rows).
// proj0 -> Q bf16 [B,H,S,D] scaled by log2(e)/8; proj1 -> K; proj2 -> V^T.
// 1-D grid, XCD swizzle: w = (f&7)*(NWG/8) + (f>>3).
__global__ __launch_bounds__(256) void gemm_qkv(
    const unsigned short* __restrict__ A, const unsigned short* __restrict__ W3,
    const float* __restrict__ bq, const float* __restrict__ bk,
    const float* __restrict__ bv, unsigned short* __restrict__ Qo,
    unsigned short* __restrict__ Ko, unsigned short* __restrict__ Vto) {
    constexpr int K = EMB;
    __shared__ __align__(16) unsigned short As[128 * 64];
    __shared__ __align__(16) unsigned short Bs[128 * 64];

    const int lane = threadIdx.x & 63;
    const int wv   = threadIdx.x >> 6;
    const int wr   = wv >> 1, wc = wv & 1;
    const int f    = blockIdx.x;                   // 0..1535
    const int w    = (f & 7) * 192 + (f >> 3);     // XCD-contiguous work id
    const int m0   = (w / 24) * 128, n0 = (w % 24) * 128;
    const int proj = n0 >> 10;
    const float* bp = proj == 0 ? bq : proj == 1 ? bk : bv;
    const float oscale = proj == 0 ? 0.18033688011112043f : 1.0f;

    f32x4 acc[4][4];
#pragma unroll
    for (int a = 0; a < 4; ++a)
#pragma unroll
        for (int b = 0; b < 4; ++b) acc[a][b] = (f32x4){0.f, 0.f, 0.f, 0.f};

    const int gsw = ((lane & 7) ^ (lane >> 3)) * 8;   // pre-swizzled src col
    for (int kt = 0; kt < K / 64; ++kt) {
        if (kt) __syncthreads();
#pragma unroll
        for (int j = 0; j < 4; ++j) {
            int rb = (wv * 4 + j) * 8;
            int r  = rb + (lane >> 3);
            gload16(A + (size_t)(m0 + r) * K + kt * 64 + gsw, &As[rb * 64]);
            gload16(W3 + (size_t)(n0 + r) * K + kt * 64 + gsw, &Bs[rb * 64]);
        }
        __syncthreads();
#pragma unroll
        for (int ks = 0; ks < 2; ++ks) {
            const int slot = ((ks * 4 + (lane >> 4)) ^ (lane & 7)) * 8;
            bf16x8 af[4], bf_[4];
#pragma unroll
            for (int x = 0; x < 4; ++x) {
                af[x]  = *(const bf16x8*)&As[(wr * 64 + x * 16 + (lane & 15)) * 64 + slot];
                bf_[x] = *(const bf16x8*)&Bs[(wc * 64 + x * 16 + (lane & 15)) * 64 + slot];
            }
#pragma unroll
            for (int mi = 0; mi < 4; ++mi)
#pragma unroll
                for (int ni = 0; ni < 4; ++ni)
                    acc[mi][ni] = __builtin_amdgcn_mfma_f32_16x16x32_bf16(
                        af[mi], bf_[ni], acc[mi][ni], 0, 0, 0);
        }
    }

#pragma unroll
    for (int mi = 0; mi < 4; ++mi) {
#pragma unroll
        for (int ni = 0; ni < 4; ++ni) {
            int n    = n0 + wc * 64 + ni * 16 + (lane & 15);
            int nloc = n & 1023;
            float bvv = bp[nloc];
            int h = nloc >> 6, d = nloc & 63;
#pragma unroll
            for (int i = 0; i < 4; ++i) {
                int m = m0 + wr * 64 + mi * 16 + (lane >> 4) * 4 + i;
                float v = (acc[mi][ni][i] + bvv) * oscale;
                int b = m >> 11, s = m & (SEQ - 1);
                if (proj == 0)
                    Qo[(((size_t)(b * NH + h) * SEQ + s) << 6) + d] = f2bf(v);
                else if (proj == 1)
                    Ko[(((size_t)(b * NH + h) * SEQ + s) << 6) + d] = f2bf(v);
                else
                    Vto[((size_t)(b * NH + h) * 64 + d) * SEQ + s] = f2bf(v);
            }
        }
    }
}

// ------------------------------------------------------- final proj GEMM ----
__global__ __launch_bounds__(256) void gemm_out(
    const unsigned short* __restrict__ A, const unsigned short* __restrict__ W,
    const float* __restrict__ bias, float* __restrict__ out) {
    constexpr int K = EMB;
    __shared__ __align__(16) unsigned short As[128 * 64];
    __shared__ __align__(16) unsigned short Bs[128 * 64];

    const int lane = threadIdx.x & 63;
    const int wv   = threadIdx.x >> 6;
    const int wr   = wv >> 1, wc = wv & 1;
    const int f    = blockIdx.x;                 // 0..511
    const int w    = (f & 7) * 64 + (f >> 3);    // XCD-contiguous work id
    const int m0   = (w / 8) * 128, n0 = (w % 8) * 128;

    f32x4 acc[4][4];
#pragma unroll
    for (int a = 0; a < 4; ++a)
#pragma unroll
        for (int b = 0; b < 4; ++b) acc[a][b] = (f32x4){0.f, 0.f, 0.f, 0.f};

    const int gsw = ((lane & 7) ^ (lane >> 3)) * 8;
    for (int kt = 0; kt < K / 64; ++kt) {
        if (kt) __syncthreads();
#pragma unroll
        for (int j = 0; j < 4; ++j) {
            int rb = (wv * 4 + j) * 8;
            int r  = rb + (lane >> 3);
            gload16(A + (size_t)(m0 + r) * K + kt * 64 + gsw, &As[rb * 64]);
            gload16(W + (size_t)(n0 + r) * K + kt * 64 + gsw, &Bs[rb * 64]);
        }
        __syncthreads();
#pragma unroll
        for (int ks = 0; ks < 2; ++ks) {
            const int slot = ((ks * 4 + (lane >> 4)) ^ (lane & 7)) * 8;
            bf16x8 af[4], bf_[4];
#pragma unroll
            for (int x = 0; x < 4; ++x) {
                af[x]  = *(const bf16x8*)&As[(wr * 64 + x * 16 + (lane & 15)) * 64 + slot];
                bf_[x] = *(const bf16x8*)&Bs[(wc * 64 + x * 16 + (lane & 15)) * 64 + slot];
            }
#pragma unroll
            for (int mi = 0; mi < 4; ++mi)
#pragma unroll
                for (int ni = 0; ni < 4; ++ni)
                    acc[mi][ni] = __builtin_amdgcn_mfma_f32_16x16x32_bf16(
                        af[mi], bf_[ni], acc[mi][ni], 0, 0, 0);
        }
    }

#pragma unroll
    for (int mi = 0; mi < 4; ++mi) {
#pragma unroll
        for (int ni = 0; ni < 4; ++ni) {
            int n = n0 + wc * 64 + ni * 16 + (lane & 15);
            float bv = bias[n];
#pragma unroll
            for (int i = 0; i < 4; ++i) {
                int m = m0 + wr * 64 + mi * 16 + (lane >> 4) * 4 + i;
                out[(size_t)m * EMB + n] = acc[mi][ni][i] + bv;
            }
        }
    }
}

// ----------------------------------------------------------- attention ----
// VERIFIED R14 version (83us, absmax 4.88e-4, 0 bank conflicts) — final.
// R9 structure + l-via-MFMA: lT = mfma(ones, pf) accumulates P column-sums
// on the matrix pipe. 512 threads, 8 waves, 32 q per wave. 1-D grid, bh in
// LOW 6 bits (XCD). Granule-major LDS. Fixed-max softmax p = exp2(s).
// Q: [B,H,S,D] bf16 PRE-SCALED by log2(e)/8; K: [B,H,S,D]; Vt: [B,H,D,S];
// AO: [B,S,H,D] bf16.
__global__ __launch_bounds__(512, 4) void attn_fwd(
    const unsigned short* __restrict__ Q, const unsigned short* __restrict__ K,
    const unsigned short* __restrict__ Vt, unsigned short* __restrict__ AO) {
    const int qt = blockIdx.x >> 6;   // 0..7 (q tile of 256)
    const int bh = blockIdx.x & 63;   // low bits -> XCD locality
    const int lane = threadIdx.x & 63;
    const int wv   = threadIdx.x >> 6;   // 0..7
    const int l31  = lane & 31;
    const int lh   = lane >> 5;

    __shared__ __align__(16) unsigned short Ks[2][8 * 64 * 8];  // [g][kv][8]
    __shared__ __align__(16) unsigned short Vs[2][8 * 64 * 8];  // [g][d][8]

    const unsigned short* Kb = K + (size_t)bh * SEQ * HD;
    const unsigned short* Vb = Vt + (size_t)bh * HD * SEQ;

    // Q B-fragments (col=q=l31, k=d): lane's q-row, half-k slice per lh
    const unsigned short* Qp = Q + ((size_t)bh * SEQ + qt * 256 + wv * 32 + l31) * HD + lh * 8;
    bf16x8 qfr[4];
#pragma unroll
    for (int kc = 0; kc < 4; ++kc) qfr[kc] = *(const bf16x8*)(Qp + kc * 16);

    // ones A-fragment (bf16 1.0 = 0x3F80)
    const u32x4 onesu = {0x3F803F80u, 0x3F803F80u, 0x3F803F80u, 0x3F803F80u};
    const bf16x8 ones = __builtin_bit_cast(bf16x8, onesu);

    f32x16 oT[2], lT;
#pragma unroll
    for (int r = 0; r < 16; ++r) { oT[0][r] = 0.f; oT[1][r] = 0.f; lT[r] = 0.f; }

    // wave w stages K-granule w (d cols w*8..w*8+7 for all 64 kv) and
    // V-granule w (kv cols t*64+w*8.. for all 64 d); linear LDS dest.
    auto stageKV = [&](int buf, int t) {
        gload16(Kb + (size_t)(t * 64 + lane) * HD + wv * 8, &Ks[buf][wv * 512]);
        gload16(Vb + (size_t)lane * SEQ + t * 64 + wv * 8, &Vs[buf][wv * 512]);
    };

    stageKV(0, 0);

    for (int t = 0; t < SEQ / 64; ++t) {
        const int cur = t & 1;
        __syncthreads();
        if (t + 1 < SEQ / 64) stageKV(cur ^ 1, t + 1);

#pragma unroll
        for (int sub = 0; sub < 2; ++sub) {
            // S^T(32kv x 32q) = K_sub · Q^T ; kf granule g = kc*2+lh, row = krow
            f32x16 st;
#pragma unroll
            for (int r = 0; r < 16; ++r) st[r] = 0.f;
            const int krow = sub * 32 + l31;
            __builtin_amdgcn_s_setprio(1);
#pragma unroll
            for (int kc = 0; kc < 4; ++kc) {
                bf16x8 kf = *(const bf16x8*)&Ks[cur][(kc * 2 + lh) * 512 + krow * 8];
                st = __builtin_amdgcn_mfma_f32_32x32x16_bf16(kf, qfr[kc], st, 0, 0, 0);
            }
            __builtin_amdgcn_s_setprio(0);

            // p = exp2(st); pack pairs to bf16 (q lane-local)
            unsigned w0, w1, w2, w3, w4, w5, w6, w7;
#define EXPPK(WI, RA, RB)                                                     \
            {                                                                 \
                float pa = __builtin_amdgcn_exp2f(st[RA]);                    \
                float pb = __builtin_amdgcn_exp2f(st[RB]);                    \
                asm("v_cvt_pk_bf16_f32 %0, %1, %2" : "=v"(WI) : "v"(pa), "v"(pb)); \
            }
            EXPPK(w0, 0, 1)  EXPPK(w1, 2, 3)  EXPPK(w2, 4, 5)  EXPPK(w3, 6, 7)
            EXPPK(w4, 8, 9)  EXPPK(w5, 10, 11) EXPPK(w6, 12, 13) EXPPK(w7, 14, 15)
#undef EXPPK
            asm volatile("v_permlane32_swap_b32 %0, %1" : "+v"(w0), "+v"(w2));
            asm volatile("v_permlane32_swap_b32 %0, %1" : "+v"(w1), "+v"(w3));
            asm volatile("v_permlane32_swap_b32 %0, %1" : "+v"(w4), "+v"(w6));
            asm volatile("v_permlane32_swap_b32 %0, %1" : "+v"(w5), "+v"(w7));
            u32x4 a0 = {w0, w1, w2, w3};
            u32x4 a1 = {w4, w5, w6, w7};
            bf16x8 pf0 = __builtin_bit_cast(bf16x8, a0);
            bf16x8 pf1 = __builtin_bit_cast(bf16x8, a1);

            // O^T += V^T_sub · P^T ; l += 1^T · P^T  (all on the MFMA pipe)
            __builtin_amdgcn_s_setprio(1);
            lT = __builtin_amdgcn_mfma_f32_32x32x16_bf16(ones, pf0, lT, 0, 0, 0);
            lT = __builtin_amdgcn_mfma_f32_32x32x16_bf16(ones, pf1, lT, 0, 0, 0);
#pragma unroll
            for (int dt = 0; dt < 2; ++dt) {
                int d = dt * 32 + l31;
#pragma unroll
                for (int ks = 0; ks < 2; ++ks) {
                    bf16x8 vf = *(const bf16x8*)&Vs[cur][(sub * 4 + ks * 2 + lh) * 512 + d * 8];
                    oT[dt] = __builtin_amdgcn_mfma_f32_32x32x16_bf16(
                        vf, ks ? pf1 : pf0, oT[dt], 0, 0, 0);
                }
            }
            __builtin_amdgcn_s_setprio(0);
        }
    }

    // l = lT[0] (every C row is the full colsum); divide and store O^T
    float inv = 1.0f / lT[0];
    const int b = bh >> 4, h = bh & 15;
    const int q = qt * 256 + wv * 32 + l31;
    unsigned short* aor = AO + (((size_t)b * SEQ + q) * NH + h) * HD;
#pragma unroll
    for (int dt = 0; dt < 2; ++dt) {
#pragma unroll
        for (int g = 0; g < 4; ++g) {
            ushort4 o;
            o.x = f2bf(oT[dt][g * 4 + 0] * inv);
            o.y = f2bf(oT[dt][g * 4 + 1] * inv);
            o.z = f2bf(oT[dt][g * 4 + 2] * inv);
            o.w = f2bf(oT[dt][g * 4 + 3] * inv);
            *(ushort4*)(aor + dt * 32 + g * 8 + lh * 4) = o;
        }
    }
}

// -------------------------------------------------------------- launch ----
extern "C" void kernel_launch(void* const* d_in, const int* in_sizes, int n_in,
                              void* d_out, int out_size, void* d_ws, size_t ws_size,
                              hipStream_t stream) {
    const float* X  = (const float*)d_in[0];
    const float* wq = (const float*)d_in[1];
    const float* bq = (const float*)d_in[2];
    const float* wk = (const float*)d_in[3];
    const float* bk = (const float*)d_in[4];
    const float* wv = (const float*)d_in[5];
    const float* bv = (const float*)d_in[6];
    const float* wo = (const float*)d_in[7];
    const float* bo = (const float*)d_in[8];
    float* out = (float*)d_out;

    unsigned short* ws = (unsigned short*)d_ws;
    const size_t XE = (size_t)MTOT * EMB;      // 8388608
    const size_t WE = (size_t)EMB * EMB;       // 1048576
    unsigned short* Xb  = ws;
    unsigned short* Wqb = ws + XE;             // Wq|Wk|Wv contiguous = W3
    unsigned short* Wkb = Wqb + WE;
    unsigned short* Wvb = Wkb + WE;
    unsigned short* Wob = Wvb + WE;
    unsigned short* Qb  = Wob + WE;
    unsigned short* Kb  = Qb + XE;
    unsigned short* Vtb = Kb + XE;
    unsigned short* AOb = Xb;                  // alias: Xb dead after QKV proj

    cast_all<<<12288, 256, 0, stream>>>(X, wq, wk, wv, wo, Xb, Wqb, Wkb, Wvb, Wob);

    gemm_qkv<<<1536, 256, 0, stream>>>(Xb, Wqb, bq, bk, bv, Qb, Kb, Vtb);

    attn_fwd<<<512, 512, 0, stream>>>(Qb, Kb, Vtb, AOb);

    gemm_out<<<512, 256, 0, stream>>>(AOb, Wob, bo, out);
}